// Round 4
// baseline (129.303 us; speedup 1.0000x reference)
//
#include <hip/hip_runtime.h>
#include <hip/hip_bf16.h>
#include <math.h>

#define B_ROWS 4096
#define D_DIM  256
#define N_TOT  8192            // 2B
#define E2     7.38905609893065f   // exp(2) = diagonal term of the row sum
#define NTILE  64              // 8192 / 128
#define NBLK   (NTILE * (NTILE + 1) / 2)   // 2080 upper-triangle tile pairs

typedef __attribute__((ext_vector_type(4))) float f32x4;

__device__ __forceinline__ void async_copy16(const void* gptr, void* lptr) {
    // NOTE: lptr is the WAVE-UNIFORM base; HW scatters lane*16 itself.
    __builtin_amdgcn_global_load_lds(
        (const __attribute__((address_space(1))) unsigned int*)gptr,
        (__attribute__((address_space(3))) unsigned int*)lptr,
        16 /*bytes*/, 0 /*offset*/, 0 /*aux*/);
}

// ---------------------------------------------------------------------------
// Kernel 1: L2-normalize query & pos -> fp8 e4m3 Z[8192][256B]; per-row
// positive dot -> pospart[row]. One WAVE per row (4 rows/block), float4
// loads, butterfly reduction, zero barriers. Blocks 0..31 zero denom[8192].
// ---------------------------------------------------------------------------
__global__ __launch_bounds__(256) void norm_kernel(
        const float* __restrict__ q, const float* __restrict__ p,
        unsigned char* __restrict__ Z, float* __restrict__ pospart,
        float* __restrict__ denom) {
    const int t    = threadIdx.x;
    const int lane = t & 63;
    const int wv   = t >> 6;
    const int row  = blockIdx.x * 4 + wv;        // 0..4095
    if (blockIdx.x < 32) denom[blockIdx.x * 256 + t] = 0.0f;

    const f32x4 q4 = *(const f32x4*)(q + (size_t)row * D_DIM + lane * 4);
    const f32x4 p4 = *(const f32x4*)(p + (size_t)row * D_DIM + lane * 4);
    float a = q4[0]*q4[0] + q4[1]*q4[1] + q4[2]*q4[2] + q4[3]*q4[3];
    float b = p4[0]*p4[0] + p4[1]*p4[1] + p4[2]*p4[2] + p4[3]*p4[3];
    float c = q4[0]*p4[0] + q4[1]*p4[1] + q4[2]*p4[2] + q4[3]*p4[3];
    #pragma unroll
    for (int off = 1; off < 64; off <<= 1) {   // butterfly: all lanes get sums
        a += __shfl_xor(a, off);
        b += __shfl_xor(b, off);
        c += __shfl_xor(c, off);
    }
    const float rq = 1.0f / fmaxf(sqrtf(a), 1e-12f);
    const float rp = 1.0f / fmaxf(sqrtf(b), 1e-12f);

    int zq = 0, zp = 0;
    zq = __builtin_amdgcn_cvt_pk_fp8_f32(q4[0]*rq, q4[1]*rq, zq, false);
    zq = __builtin_amdgcn_cvt_pk_fp8_f32(q4[2]*rq, q4[3]*rq, zq, true);
    zp = __builtin_amdgcn_cvt_pk_fp8_f32(p4[0]*rp, p4[1]*rp, zp, false);
    zp = __builtin_amdgcn_cvt_pk_fp8_f32(p4[2]*rp, p4[3]*rp, zp, true);
    ((int*)(Z + (size_t)row * D_DIM))[lane]            = zq;
    ((int*)(Z + (size_t)(B_ROWS + row) * D_DIM))[lane] = zp;
    if (lane == 0) pospart[row] = c * rq * rp;
}

// ---------------------------------------------------------------------------
// Kernel 2: fused S = Z*Z^T (fp8 e4m3), upper-triangle tile pairs, epilogue
// rowsum += sum_j exp(2*S). 128x128 tile, BK=128 (2 K-iters only), LDS
// 16+16 KB -> 5 blocks/CU (20 waves/CU). Z is 2 MB: fits every XCD L2, so
// staging hits L2 after first touch. XOR swizzle on the global source side
// keeps both global_load_lds writes and ds_read_b64 bank-balanced.
// Both MFMA operands use the SAME lane->k mapping, so the Gram product is
// layout-permutation-invariant (k-order cancels between A and B).
// ---------------------------------------------------------------------------
__global__ __launch_bounds__(256, 5) void simexp_gemm(
        const unsigned char* __restrict__ Z, float* __restrict__ denom) {
    __shared__ unsigned char As[128 * 128];   // 16 KB, row stride 128 B
    __shared__ unsigned char Bs[128 * 128];   // 16 KB
    const int tid    = threadIdx.x;
    const int lane   = tid & 63;
    const int wv     = tid >> 6;      // wave id 0..3
    const int wave_m = wv >> 1;       // 0..1  (row half)
    const int wave_n = wv & 1;        // 0..1  (col half)
    const int m16    = lane & 15;
    const int quad   = lane >> 4;

    // --- triangular decode: bid -> (bi <= bj) ---
    const int bid = blockIdx.x;
    int bi = (int)((129.0 - sqrt(129.0 * 129.0 - 8.0 * (double)bid)) * 0.5);
    while (bi > 0 && (bi * NTILE - bi * (bi - 1) / 2) > bid) --bi;
    while (((bi + 1) * NTILE - (bi + 1) * bi / 2) <= bid) ++bi;
    const int bj = bi + (bid - (bi * NTILE - bi * (bi - 1) / 2));
    const int rowBase = bi * 128;
    const int colBase = bj * 128;

    f32x4 acc[4][4];
    #pragma unroll
    for (int i = 0; i < 4; ++i)
        #pragma unroll
        for (int j = 0; j < 4; ++j) acc[i][j] = (f32x4){0.f, 0.f, 0.f, 0.f};

    // staging: one instr = 64 lanes x 16B = 8 rows of 128 B.
    // lane l -> local row (l>>3), chunk slot (l&7); LDS chunk c of row r
    // holds global chunk c ^ (r&7) (xor involution).
    const int lrow = lane >> 3;        // 0..7 within an 8-row group
    const int lchk = lane & 7;         // 16B chunk slot

    for (int kt = 0; kt < 2; ++kt) {
        const int k0 = kt * 128;               // byte offset in K (1B/elem)
        __syncthreads();   // previous iter's LDS reads done before overwrite
        #pragma unroll
        for (int pp = 0; pp < 4; ++pp) {
            const int r = wv * 32 + pp * 8 + lrow;      // local row 0..127
            const int g = lchk ^ (r & 7);               // swizzled global chunk
            const unsigned char* srcA =
                Z + (size_t)(rowBase + r) * D_DIM + k0 + g * 16;
            const unsigned char* srcB =
                Z + (size_t)(colBase + r) * D_DIM + k0 + g * 16;
            async_copy16(srcA, As + (wv * 32 + pp * 8) * 128);
            async_copy16(srcB, Bs + (wv * 32 + pp * 8) * 128);
        }
        __syncthreads();   // drains vmcnt: staging complete

        #pragma unroll
        for (int kt2 = 0; kt2 < 4; ++kt2) {
            // fragment: 8 fp8 at row r, k-bytes kt2*32 + quad*8 .. +8
            const int chunk = kt2 * 2 + (quad >> 1);        // 16B chunk index
            const int half  = (quad & 1) * 8;
            const int sc    = chunk ^ (m16 & 7);            // swizzled
            long af[4], bfr[4];
            #pragma unroll
            for (int mi = 0; mi < 4; ++mi) {
                const int r = wave_m * 64 + mi * 16 + m16;
                af[mi] = *(const long*)(As + r * 128 + sc * 16 + half);
            }
            #pragma unroll
            for (int ni = 0; ni < 4; ++ni) {
                const int r = wave_n * 64 + ni * 16 + m16;
                bfr[ni] = *(const long*)(Bs + r * 128 + sc * 16 + half);
            }
            #pragma unroll
            for (int mi = 0; mi < 4; ++mi)
                #pragma unroll
                for (int ni = 0; ni < 4; ++ni)
                    acc[mi][ni] = __builtin_amdgcn_mfma_f32_16x16x32_fp8_fp8(
                        af[mi], bfr[ni], acc[mi][ni], 0, 0, 0);
        }
    }

    // --- epilogue: exp(2s) once; accumulate row partials and col partials ---
    // C/D layout: col = lane&15, row = quad*4 + reg  [m89-verified,
    // dtype-independent on gfx950].
    float cs[4] = {0.f, 0.f, 0.f, 0.f};
    float rs[4][4];
    #pragma unroll
    for (int mi = 0; mi < 4; ++mi)
        #pragma unroll
        for (int r = 0; r < 4; ++r) {
            float s = 0.f;
            #pragma unroll
            for (int ni = 0; ni < 4; ++ni) {
                const float e = __expf(2.0f * acc[mi][ni][r]);
                s += e;
                cs[ni] += e;
            }
            rs[mi][r] = s;
        }
    // row sums: reduce across the 16 columns (lanes sharing a quad)
    #pragma unroll
    for (int off = 1; off < 16; off <<= 1)
        #pragma unroll
        for (int mi = 0; mi < 4; ++mi)
            #pragma unroll
            for (int r = 0; r < 4; ++r)
                rs[mi][r] += __shfl_xor(rs[mi][r], off, 64);
    if (m16 == 0) {
        #pragma unroll
        for (int mi = 0; mi < 4; ++mi)
            #pragma unroll
            for (int r = 0; r < 4; ++r)
                atomicAdd(&denom[rowBase + wave_m * 64 + mi * 16 + quad * 4 + r],
                          rs[mi][r]);
    }
    // col sums: reduce across the 4 quads (rows) -> symmetric contribution
    if (bi != bj) {
        #pragma unroll
        for (int off = 16; off < 64; off <<= 1)
            #pragma unroll
            for (int ni = 0; ni < 4; ++ni)
                cs[ni] += __shfl_xor(cs[ni], off, 64);
        if (lane < 16) {
            #pragma unroll
            for (int ni = 0; ni < 4; ++ni)
                atomicAdd(&denom[colBase + wave_n * 64 + ni * 16 + m16], cs[ni]);
        }
    }
}

// ---------------------------------------------------------------------------
// Kernel 3: loss = (sum_i log(denom_i - e^2) - 4*sum_i pospart_i) / 8192
// ---------------------------------------------------------------------------
__global__ __launch_bounds__(256) void finalize_kernel(
        const float* __restrict__ denom, const float* __restrict__ pospart,
        float* __restrict__ out) {
    const int t = threadIdx.x;
    float s = 0.f;
    #pragma unroll
    for (int i = 0; i < N_TOT / 256; ++i) s += logf(denom[i * 256 + t] - E2);
    float pp = 0.f;
    #pragma unroll
    for (int i = 0; i < B_ROWS / 256; ++i) pp += pospart[i * 256 + t];
    s -= 4.0f * pp;
    #pragma unroll
    for (int off = 32; off > 0; off >>= 1) s += __shfl_down(s, off);
    __shared__ float red[4];
    if ((t & 63) == 0) red[t >> 6] = s;
    __syncthreads();
    if (t == 0)
        out[0] = (red[0] + red[1] + red[2] + red[3]) / (float)N_TOT;
}

extern "C" void kernel_launch(void* const* d_in, const int* in_sizes, int n_in,
                              void* d_out, int out_size, void* d_ws, size_t ws_size,
                              hipStream_t stream) {
    const float* q = (const float*)d_in[0];
    const float* p = (const float*)d_in[1];
    // d_in[2] (neg) is normalized in the original but never used in the loss.
    float* out = (float*)d_out;

    // Workspace: Z fp8 [8192*256] (2 MiB) | denom f32 [8192] | pospart f32 [4096]
    unsigned char* Z = (unsigned char*)d_ws;
    float* denom   = (float*)((char*)d_ws + (size_t)N_TOT * D_DIM);
    float* pospart = denom + N_TOT;

    hipLaunchKernelGGL(norm_kernel, dim3(B_ROWS / 4), dim3(256), 0, stream,
                       q, p, Z, pospart, denom);
    hipLaunchKernelGGL(simexp_gemm, dim3(NBLK), dim3(256), 0, stream, Z, denom);
    hipLaunchKernelGGL(finalize_kernel, dim3(1), dim3(256), 0, stream,
                       denom, pospart, out);
}